// Round 6
// baseline (14245.146 us; speedup 1.0000x reference)
//
#include <hip/hip_runtime.h>
#include <hip/hip_fp16.h>

#define B_ 64
#define T_ 512
#define EMB_ 128
#define HID_ 256
#define MEL_ 80

typedef __attribute__((ext_vector_type(8))) _Float16 half8;
typedef __attribute__((ext_vector_type(4))) float f32x4;
typedef __attribute__((ext_vector_type(4))) unsigned int u32x4;

__device__ __forceinline__ float sigf(float x) {
  x = fminf(fmaxf(x, -30.f), 30.f);
  return 1.f / (1.f + __expf(-x));
}
__device__ __forceinline__ float tanhf_(float x) {
  x = fminf(fmaxf(x, -15.f), 15.f);
  float e = __expf(2.f * x);
  return (e - 1.f) / (e + 1.f);
}

// Barrier that drains ONLY LDS (lgkmcnt), not vmcnt: publish stores and poll
// loads stay in flight across it. All cross-wave data handoff here is LDS.
__device__ __forceinline__ void barrier_lds() {
  __builtin_amdgcn_sched_barrier(0);
  asm volatile("s_waitcnt lgkmcnt(0)" ::: "memory");
  __builtin_amdgcn_s_barrier();
  __builtin_amdgcn_sched_barrier(0);
}

// L1-bypassing load attempt (sc0). Result NOT valid until wait_vm0().
__device__ __forceinline__ void issue_sc0(unsigned int* d, const unsigned int* p) {
  asm volatile("global_load_dword %0, %1, off sc0" : "=v"(*d) : "v"(p));
}
__device__ __forceinline__ void wait_vm0() {
  __builtin_amdgcn_sched_barrier(0);
  asm volatile("s_waitcnt vmcnt(0)" ::: "memory");
  __builtin_amdgcn_sched_barrier(0);
}

// Pack W=[wih|whh] (per dir 1024x384) into MFMA B-frags with PER-BLOCK K order:
// [ x(0..127) | own-slice h(64) | remote slices in ascending-slice order (192) ].
// Rows permuted to gu-order (wave wv owns units wv*16.., gates via nt=wv+4g).
// Wall[((ds*16+nt)*12+kt)*64 + lane][8]
__global__ void k_pack_wall(const float* __restrict__ wih_f, const float* __restrict__ whh_f,
                            const float* __restrict__ wih_b, const float* __restrict__ whh_b,
                            _Float16* __restrict__ Wall) {
  int tid = blockIdx.x * 256 + threadIdx.x;  // 98304 total
  int lane = tid & 63;
  int r = tid >> 6;
  int kt = r % 12; r /= 12;
  int nt = r % 16; r /= 16;
  int ds = r;  // 0..7
  if (ds >= 8) return;
  int dir = ds >> 2, slice = ds & 3;
  const float* wih = dir ? wih_b : wih_f;
  const float* whh = dir ? whh_b : whh_f;
  int gu = nt * 16 + (lane & 15);
  int g = gu >> 6, u = gu & 63;
  int row = g * 256 + slice * 64 + u;
  int kbase = kt * 32 + (lane >> 4) * 8;
  _Float16* dst = Wall + (size_t)tid * 8;
#pragma unroll
  for (int j = 0; j < 8; ++j) {
    int k = kbase + j;
    float v;
    if (k < EMB_) {
      v = wih[row * EMB_ + k];
    } else if (k < EMB_ + 64) {
      v = whh[row * HID_ + slice * 64 + (k - EMB_)];
    } else {
      int jx = k - (EMB_ + 64);
      int rr = jx >> 6;
      int ps = rr + (rr >= slice ? 1 : 0);
      v = whh[row * HID_ + ps * 64 + (jx & 63)];
    }
    dst[j] = (_Float16)v;
  }
}

__global__ void k_pack_misc(const float* __restrict__ bih_f, const float* __restrict__ bhh_f,
                            const float* __restrict__ bih_b, const float* __restrict__ bhh_b,
                            const float* __restrict__ lin_w, float* __restrict__ bsum,
                            _Float16* __restrict__ linWp) {
  int t = blockIdx.x * 256 + threadIdx.x;
  if (t < 2048) {
    int dir = t >> 10, g = t & 1023;
    bsum[t] = dir ? (bih_b[g] + bhh_b[g]) : (bih_f[g] + bhh_f[g]);
  } else if (t < 2048 + 5120) {
    int u = t - 2048;
    int lane = u & 63;
    int r = u >> 6;
    int kt = r % 16, nt = r / 16;
    int n = nt * 16 + (lane & 15);
    int kbase = kt * 32 + (lane >> 4) * 8;
    _Float16* dst = linWp + (size_t)u * 8;
#pragma unroll
    for (int j = 0; j < 8; ++j) dst[j] = (_Float16)lin_w[n * 512 + kbase + j];
  }
}

__global__ void k_dur(const int* __restrict__ x, const float* __restrict__ embed,
                      const float* __restrict__ dp_w, const float* __restrict__ dp_b,
                      int* __restrict__ dur) {
  int gid = blockIdx.x * 256 + threadIdx.x;
  if (gid >= B_ * T_) return;
  const float* er = embed + (size_t)x[gid] * EMB_;
  float d = 0.f;
  for (int e = 0; e < EMB_; ++e) d += er[e] * dp_w[e];
  d += dp_b[0];
  d = fmaxf(d, 0.f);
  dur[gid] = (int)floorf(d) + 1;
}

__global__ void k_scan(const int* __restrict__ dur, int* __restrict__ cum) {
  __shared__ int s[512];
  int b = blockIdx.x, t = threadIdx.x;
  s[t] = dur[b * 512 + t];
  __syncthreads();
  for (int off = 1; off < 512; off <<= 1) {
    int v = (t >= off) ? s[t - off] : 0;
    __syncthreads();
    s[t] += v;
    __syncthreads();
  }
  cum[b * 512 + t] = s[t];
}

__global__ void k_fill(int* __restrict__ p, int n, int v) {
  int gid = blockIdx.x * 256 + threadIdx.x;
  if (gid < n) p[gid] = v;
}

// sentinel-fill mailbox (0xFFFFFFFF = fp16 NaN pair, impossible as real h)
__global__ void k_fill_sent(unsigned int* __restrict__ p, int n4) {
  int gid = blockIdx.x * 256 + threadIdx.x;
  if (gid < n4) ((u32x4*)p)[gid] = u32x4{0xFFFFFFFFu, 0xFFFFFFFFu, 0xFFFFFFFFu, 0xFFFFFFFFu};
}

__global__ void k_scatter(const int* __restrict__ cum, int* __restrict__ idx, int L) {
  int b = blockIdx.x, t = threadIdx.x;
  int c1 = cum[b * 512 + t];
  int c0 = t ? cum[b * 512 + t - 1] : 0;
  for (int p = c0; p < c1; ++p)
    if (p < L) idx[(size_t)b * L + p] = t;
}

__global__ void k_expand(const int* __restrict__ x, const float* __restrict__ embed,
                         const int* __restrict__ idx, _Float16* __restrict__ expb, int L) {
  int gid = blockIdx.x * 256 + threadIdx.x;
  if (gid >= B_ * L * 16) return;
  int ch = gid & 15;
  int rem = gid >> 4;
  int l = rem % L;
  int b = rem / L;
  int ix = idx[(size_t)b * L + l];
  half8 v;
  if (ix < 0) {
#pragma unroll
    for (int j = 0; j < 8; ++j) v[j] = (_Float16)0.f;
  } else {
    const float* er = embed + (size_t)x[b * 512 + ix] * EMB_ + ch * 8;
#pragma unroll
    for (int j = 0; j < 8; ++j) v[j] = (_Float16)er[j];
  }
  *(half8*)(expb + ((size_t)b * L + l) * EMB_ + ch * 8) = v;
}

// 8 worker blocks = 2 dirs x 4 hidden-slices (grid=26; workers at bid%8 in
// {0,1} so each dir's 4 blocks share one XCD under round-robin placement,
// runtime-verified via HW_REG_XCC_ID). Publish is ALWAYS dual (agent store ->
// memory-side guarantee, then plain store -> fast local-L2 copy). Polling:
// fast mode = tier1 sc0 loads (<=8 rounds) -> tier2 L2-atomic read (<=16
// rounds, atomics execute at L2, never L1) -> tier3 agent loads (terminate
// guaranteed by dual publish). Fallback mode = R4 agent protocol. Every wait
// bounded or backed: the kernel cannot hang.
__global__ __launch_bounds__(256, 1) void k_rec(
    const _Float16* __restrict__ expb, const _Float16* __restrict__ Wall,
    const float* __restrict__ bsum, _Float16* __restrict__ mail,
    int* __restrict__ xccTab, int L) {
  int r8 = blockIdx.x & 7;
  if (r8 >= 2) return;  // placeholder block
  int dir = r8, slice = blockIdx.x >> 3;
  int ds = dir * 4 + slice;

  __shared__ __align__(16) _Float16 Ash[64][392];  // [b][ x(128) | own(64) | remote(192) | pad ]
  __shared__ int sFast;
  int tid = threadIdx.x;
  int wv = tid >> 6, lane = tid & 63;
  int c = lane & 15, kg = lane >> 4;
  unsigned int* mail32 = (unsigned int*)mail;
  int cb = tid >> 2, q = tid & 3;  // consumer: batch cb, word-lane q
  int s32 = slice * 32;

  for (int i = tid; i < 64 * 392 / 8; i += 256)
    ((half8*)&Ash[0][0])[i] = half8{0, 0, 0, 0, 0, 0, 0, 0};
  float bias[4];
#pragma unroll
  for (int g = 0; g < 4; ++g)
    bias[g] = bsum[dir * 1024 + g * 256 + slice * 64 + wv * 16 + c];
  half8 breg[4][12];
#pragma unroll
  for (int g = 0; g < 4; ++g) {
    int nt = wv + 4 * g;
#pragma unroll
    for (int kt = 0; kt < 12; ++kt)
      breg[g][kt] = *(const half8*)(Wall + (((size_t)(ds * 16 + nt) * 12 + kt) * 64 + lane) * 8);
  }
  float creg[16];
#pragma unroll
  for (int i = 0; i < 16; ++i) creg[i] = 0.f;

  // --- bounded placement detection: all 4 blocks of my dir on one XCD? ---
  unsigned int myxcc;
  asm volatile("s_getreg_b32 %0, hwreg(HW_REG_XCC_ID)" : "=s"(myxcc));
  if (tid == 0) {
    __hip_atomic_store(&xccTab[ds], (int)(myxcc & 0xF) + 1, __ATOMIC_RELEASE,
                       __HIP_MEMORY_SCOPE_AGENT);
    int v0 = 0, v1 = 0, v2 = 0, v3 = 0;
    for (int it = 0; it < (1 << 14); ++it) {
      v0 = __hip_atomic_load(&xccTab[dir * 4 + 0], __ATOMIC_ACQUIRE, __HIP_MEMORY_SCOPE_AGENT);
      v1 = __hip_atomic_load(&xccTab[dir * 4 + 1], __ATOMIC_ACQUIRE, __HIP_MEMORY_SCOPE_AGENT);
      v2 = __hip_atomic_load(&xccTab[dir * 4 + 2], __ATOMIC_ACQUIRE, __HIP_MEMORY_SCOPE_AGENT);
      v3 = __hip_atomic_load(&xccTab[dir * 4 + 3], __ATOMIC_ACQUIRE, __HIP_MEMORY_SCOPE_AGENT);
      if (v0 && v1 && v2 && v3) break;
      __builtin_amdgcn_s_sleep(8);
    }
    sFast = (v0 && v1 && v2 && v3 && v0 == v1 && v1 == v2 && v2 == v3) ? 1 : 0;
  }
  __syncthreads();
  const bool fastOK = (sFast != 0);
  {  // x_0
    int l0 = dir ? (L - 1) : 0;
#pragma unroll
    for (int r = 0; r < 4; ++r) {
      int f = tid + 256 * r;
      int b = f >> 4, ch = f & 15;
      *(half8*)&Ash[b][ch * 8] = *(const half8*)(expb + ((size_t)b * L + l0) * EMB_ + ch * 8);
    }
  }
  __syncthreads();

  for (int s = 0; s < L; ++s) {
    int l_io = dir ? (L - 1 - s) : s;
    // --- p0: issue poll loads for remote h_{s-1} + x(s+1) prefetch ---
    unsigned int v[24];
    unsigned int* rp = nullptr;
    if (s > 0) {
      int l_prev = dir ? (L - s) : (s - 1);
      rp = mail32 + ((size_t)(l_prev * 2 + dir) * 64 + cb) * 128;
      if (fastOK) {
#pragma unroll
        for (int wd = 0; wd < 24; ++wd) {
          int j32 = wd * 4 + q;
          int jm = j32 + (j32 >= s32 ? 32 : 0);
          issue_sc0(&v[wd], rp + jm);
        }
      } else {
#pragma unroll
        for (int wd = 0; wd < 24; ++wd) {
          int j32 = wd * 4 + q;
          int jm = j32 + (j32 >= s32 ? 32 : 0);
          v[wd] = __hip_atomic_load(rp + jm, __ATOMIC_RELAXED, __HIP_MEMORY_SCOPE_AGENT);
        }
      }
    }
    half8 xr[4];
    if (s + 1 < L) {
      int l1 = dir ? (L - 2 - s) : (s + 1);
#pragma unroll
      for (int r = 0; r < 4; ++r) {
        int f = tid + 256 * r;
        int b = f >> 4, ch = f & 15;
        xr[r] = *(const half8*)(expb + ((size_t)b * L + l1) * EMB_ + ch * 8);
      }
    }
    // --- p1: GEMM-A (x_s + own h_{s-1}), overlaps poll flight ---
    f32x4 acc[4][4];
#pragma unroll
    for (int m = 0; m < 4; ++m)
#pragma unroll
      for (int g = 0; g < 4; ++g) acc[m][g] = f32x4{0.f, 0.f, 0.f, 0.f};
#pragma unroll
    for (int kt = 0; kt < 6; ++kt) {
      half8 a[4];
#pragma unroll
      for (int m = 0; m < 4; ++m) a[m] = *(const half8*)&Ash[m * 16 + c][kt * 32 + kg * 8];
#pragma unroll
      for (int m = 0; m < 4; ++m)
#pragma unroll
        for (int g = 0; g < 4; ++g)
          acc[m][g] = __builtin_amdgcn_mfma_f32_16x16x32_f16(a[m], breg[g][kt], acc[m][g], 0, 0, 0);
    }
    // --- p2: validate polls (tiered, every wait bounded or backed) ---
    if (s > 0) {
      if (fastOK) {
        wait_vm0();
        int rounds = 0;
        while (true) {
          int miss = 0;
#pragma unroll
          for (int wd = 0; wd < 24; ++wd) miss |= (v[wd] == 0xFFFFFFFFu) ? 1 : 0;
          if (!__any(miss)) break;
          ++rounds;
          if (rounds <= 8) {  // tier 1: sc0 re-issue
            __builtin_amdgcn_s_sleep(1);
#pragma unroll
            for (int wd = 0; wd < 24; ++wd)
              if (v[wd] == 0xFFFFFFFFu) {
                int j32 = wd * 4 + q;
                int jm = j32 + (j32 >= s32 ? 32 : 0);
                issue_sc0(&v[wd], rp + jm);
              }
            wait_vm0();
          } else if (rounds <= 24) {  // tier 2: L2-executed atomic read
            __builtin_amdgcn_s_sleep(2);
#pragma unroll
            for (int wd = 0; wd < 24; ++wd)
              if (v[wd] == 0xFFFFFFFFu) {
                int j32 = wd * 4 + q;
                int jm = j32 + (j32 >= s32 ? 32 : 0);
                v[wd] = __hip_atomic_fetch_add(rp + jm, 0u, __ATOMIC_RELAXED,
                                               __HIP_MEMORY_SCOPE_WORKGROUP);
              }
          } else {  // tier 3: agent loads (dual publish guarantees progress)
            __builtin_amdgcn_s_sleep(4);
#pragma unroll
            for (int wd = 0; wd < 24; ++wd)
              if (v[wd] == 0xFFFFFFFFu) {
                int j32 = wd * 4 + q;
                int jm = j32 + (j32 >= s32 ? 32 : 0);
                v[wd] = __hip_atomic_load(rp + jm, __ATOMIC_RELAXED, __HIP_MEMORY_SCOPE_AGENT);
              }
          }
        }
      } else {  // R4-proven agent protocol
        while (true) {
          int miss = 0;
#pragma unroll
          for (int wd = 0; wd < 24; ++wd) miss |= (v[wd] == 0xFFFFFFFFu) ? 1 : 0;
          if (!__any(miss)) break;
          __builtin_amdgcn_s_sleep(2);
#pragma unroll
          for (int wd = 0; wd < 24; ++wd)
            if (v[wd] == 0xFFFFFFFFu) {
              int j32 = wd * 4 + q;
              int jm = j32 + (j32 >= s32 ? 32 : 0);
              v[wd] = __hip_atomic_load(rp + jm, __ATOMIC_RELAXED, __HIP_MEMORY_SCOPE_AGENT);
            }
        }
      }
      unsigned int* ar = (unsigned int*)&Ash[cb][0];
#pragma unroll
      for (int wd = 0; wd < 24; ++wd) ar[96 + wd * 4 + q] = v[wd];
    }
    barrier_lds();  // B1
    // --- p3: x(s+1) -> Ash (region free after GEMM-A) ---
    if (s + 1 < L) {
#pragma unroll
      for (int r = 0; r < 4; ++r) {
        int f = tid + 256 * r;
        int b = f >> 4, ch = f & 15;
        *(half8*)&Ash[b][ch * 8] = xr[r];
      }
    }
    // --- p4: GEMM-B (remote h) ---
#pragma unroll
    for (int kt = 6; kt < 12; ++kt) {
      half8 a[4];
#pragma unroll
      for (int m = 0; m < 4; ++m) a[m] = *(const half8*)&Ash[m * 16 + c][kt * 32 + kg * 8];
#pragma unroll
      for (int m = 0; m < 4; ++m)
#pragma unroll
        for (int g = 0; g < 4; ++g)
          acc[m][g] = __builtin_amdgcn_mfma_f32_16x16x32_f16(a[m], breg[g][kt], acc[m][g], 0, 0, 0);
    }
    // --- p5: cell update ---
    _Float16 hv[16];
#pragma unroll
    for (int m = 0; m < 4; ++m)
#pragma unroll
      for (int i = 0; i < 4; ++i) {
        float iv = acc[m][0][i] + bias[0];
        float fv = acc[m][1][i] + bias[1];
        float gv = acc[m][2][i] + bias[2];
        float ov = acc[m][3][i] + bias[3];
        float cc = sigf(fv) * creg[m * 4 + i] + sigf(iv) * tanhf_(gv);
        float hh = sigf(ov) * tanhf_(cc);
        creg[m * 4 + i] = cc;
        hv[m * 4 + i] = (_Float16)hh;
      }
    // --- p6: publish h_s: agent store (memory-side guarantee) + plain store ---
#pragma unroll
    for (int m = 0; m < 4; ++m)
#pragma unroll
      for (int i = 0; i < 4; ++i) {
        int id = m * 4 + i;
        unsigned int mine = (unsigned int)__builtin_bit_cast(unsigned short, hv[id]);
        unsigned int part = (unsigned int)(unsigned)__shfl_xor((int)mine, 1, 64);
        unsigned int word = (c & 1) ? ((mine << 16) | part) : (mine | (part << 16));
        if (((c & 1) == 0) == (m < 2)) {
          int b = m * 16 + kg * 4 + i;
          unsigned int* pw =
              mail32 + ((size_t)(l_io * 2 + dir) * 64 + b) * 128 + slice * 32 + wv * 8 + (c >> 1);
          __hip_atomic_store(pw, word, __ATOMIC_RELAXED, __HIP_MEMORY_SCOPE_AGENT);
          *pw = word;
        }
      }
    // --- p7: own h -> Ash ---
#pragma unroll
    for (int m = 0; m < 4; ++m)
#pragma unroll
      for (int i = 0; i < 4; ++i)
        Ash[m * 16 + kg * 4 + i][EMB_ + wv * 16 + c] = hv[m * 4 + i];
    barrier_lds();  // B2
  }
}

// out[r,:80] = h(b,l) @ lin_w.T + lin_b, reading from mailbox [l][dir][b][u]
__global__ __launch_bounds__(256) void k_linear(
    const _Float16* __restrict__ mail, const _Float16* __restrict__ linWp,
    const float* __restrict__ lin_b, float* __restrict__ out, int L) {
  int tid = threadIdx.x;
  int wv = tid >> 6, lane = tid & 63;
  int arow = lane & 15, kgrp = lane >> 4;
  int mt = blockIdx.x * 4 + wv;  // < 4L
  int r0 = mt * 16 + arow;       // A-row = b*L + l
  int b = r0 / L, l = r0 - b * L;
  const _Float16* base0 = mail + ((size_t)(l * 2 + 0) * 64 + b) * 256 + kgrp * 8;
  const _Float16* base1 = mail + ((size_t)(l * 2 + 1) * 64 + b) * 256 + kgrp * 8;
  half8 a[16];
#pragma unroll
  for (int kt = 0; kt < 8; ++kt) a[kt] = *(const half8*)(base0 + kt * 32);
#pragma unroll
  for (int kt = 8; kt < 16; ++kt) a[kt] = *(const half8*)(base1 + (kt - 8) * 32);
#pragma unroll
  for (int nt = 0; nt < 5; ++nt) {
    f32x4 acc = {0.f, 0.f, 0.f, 0.f};
    const half8* Bp = (const half8*)(linWp + (size_t)nt * 16 * 512) + lane;
#pragma unroll
    for (int kt = 0; kt < 16; ++kt)
      acc = __builtin_amdgcn_mfma_f32_16x16x32_f16(a[kt], Bp[kt * 64], acc, 0, 0, 0);
    int col = nt * 16 + arow;
    float bb = lin_b[col];
#pragma unroll
    for (int i = 0; i < 4; ++i)
      out[(size_t)(mt * 16 + kgrp * 4 + i) * MEL_ + col] = acc[i] + bb;
  }
}

extern "C" void kernel_launch(void* const* d_in, const int* in_sizes, int n_in,
                              void* d_out, int out_size, void* d_ws, size_t ws_size,
                              hipStream_t stream) {
  const int* x = (const int*)d_in[0];
  const float* embed = (const float*)d_in[1];
  const float* dp_w = (const float*)d_in[2];
  const float* dp_b = (const float*)d_in[3];
  const float* wih_f = (const float*)d_in[4];
  const float* whh_f = (const float*)d_in[5];
  const float* bih_f = (const float*)d_in[6];
  const float* bhh_f = (const float*)d_in[7];
  const float* wih_b = (const float*)d_in[8];
  const float* whh_b = (const float*)d_in[9];
  const float* bih_b = (const float*)d_in[10];
  const float* bhh_b = (const float*)d_in[11];
  const float* lin_w = (const float*)d_in[12];
  const float* lin_b = (const float*)d_in[13];
  float* out = (float*)d_out;
  (void)in_sizes; (void)n_in; (void)ws_size;

  int L = out_size / (B_ * MEL_);
  char* base = (char*)d_ws;
  size_t o = 0;
  auto take = [&](size_t bytes) {
    void* p = base + o;
    o = (o + bytes + 255) & ~(size_t)255;
    return p;
  };
  int* dur = (int*)take((size_t)B_ * T_ * 4);
  int* cum = (int*)take((size_t)B_ * T_ * 4);
  int* idx = (int*)take((size_t)B_ * L * 4);
  _Float16* Wall = (_Float16*)take((size_t)8 * 16 * 12 * 512 * 2);
  float* bsum = (float*)take(2048 * 4);
  _Float16* linWp = (_Float16*)take((size_t)5 * 16 * 512 * 2);
  int* xccTab = (int*)take(64 * 4);
  _Float16* expb = (_Float16*)take((size_t)B_ * L * EMB_ * 2);
  _Float16* mail = (_Float16*)take((size_t)L * 2 * 64 * 256 * 2);

  hipLaunchKernelGGL(k_pack_wall, dim3(384), dim3(256), 0, stream, wih_f, whh_f, wih_b, whh_b, Wall);
  hipLaunchKernelGGL(k_pack_misc, dim3(28), dim3(256), 0, stream, bih_f, bhh_f, bih_b, bhh_b,
                     lin_w, bsum, linWp);
  hipLaunchKernelGGL(k_dur, dim3(128), dim3(256), 0, stream, x, embed, dp_w, dp_b, dur);
  hipLaunchKernelGGL(k_scan, dim3(64), dim3(512), 0, stream, dur, cum);
  hipLaunchKernelGGL(k_fill, dim3((B_ * L + 255) / 256), dim3(256), 0, stream, idx, B_ * L, -1);
  hipLaunchKernelGGL(k_fill, dim3(1), dim3(256), 0, stream, xccTab, 64, 0);
  {
    int n4 = L * 4096;  // mailbox u32 count / 4
    hipLaunchKernelGGL(k_fill_sent, dim3((n4 + 255) / 256), dim3(256), 0, stream,
                       (unsigned int*)mail, n4);
  }
  hipLaunchKernelGGL(k_scatter, dim3(64), dim3(512), 0, stream, cum, idx, L);
  hipLaunchKernelGGL(k_expand, dim3((B_ * L * 16 + 255) / 256), dim3(256), 0, stream,
                     x, embed, idx, expb, L);
  hipLaunchKernelGGL(k_rec, dim3(26), dim3(256), 0, stream, expb, Wall, bsum, mail, xccTab, L);
  hipLaunchKernelGGL(k_linear, dim3(L), dim3(256), 0, stream, mail, linWp, lin_b, out, L);
}

// Round 8
// 1926.734 us; speedup vs baseline: 7.3934x; 7.3934x over previous
//
#include <hip/hip_runtime.h>
#include <hip/hip_fp16.h>

#define B_ 64
#define T_ 512
#define EMB_ 128
#define HID_ 256
#define MEL_ 80
#define LOG2E 1.44269504f

typedef __attribute__((ext_vector_type(8))) _Float16 half8;
typedef __attribute__((ext_vector_type(4))) float f32x4;
typedef __attribute__((ext_vector_type(4))) unsigned int u32x4;

// raw HW transcendentals (~1e-6 rel err, far below fp16 h quantization).
// Graceful at extremes: exp2->inf => rcp->0 (no NaN).
__device__ __forceinline__ float exp2_asm(float x) {
  float r;
  asm("v_exp_f32 %0, %1" : "=v"(r) : "v"(x));
  return r;
}
__device__ __forceinline__ float rcp_asm(float x) {
  float r;
  asm("v_rcp_f32 %0, %1" : "=v"(r) : "v"(x));
  return r;
}
// x' is log2e-prescaled (folded into weights+bias)
__device__ __forceinline__ float sig2(float xp) { return rcp_asm(1.f + exp2_asm(-xp)); }
// pass x2 = 2*log2e*y ; tanh(y) = 1 - 2/(1+e^{2y})
__device__ __forceinline__ float tanh2(float x2) { return 1.f - 2.f * rcp_asm(1.f + exp2_asm(x2)); }

// Barrier that drains ONLY LDS (lgkmcnt), not vmcnt: publish stores and poll
// loads stay in flight across it. All cross-wave data handoff here is LDS.
__device__ __forceinline__ void barrier_lds() {
  __builtin_amdgcn_sched_barrier(0);
  asm volatile("s_waitcnt lgkmcnt(0)" ::: "memory");
  __builtin_amdgcn_s_barrier();
  __builtin_amdgcn_sched_barrier(0);
}

// Pack W=[wih|whh] (per dir 1024x384) into MFMA B-frags with PER-BLOCK K order:
// [ x(0..127) | own-slice h(64) | remote slices ascending (192) ]. Rows in
// gu-order (wave wv owns units wv*16.., gates via nt=wv+4g). Weights are
// PRE-SCALED by log2e so gate pre-acts arrive ready for exp2-based nonlins.
// Wall[((ds*16+nt)*12+kt)*64 + lane][8]
__global__ void k_pack_wall(const float* __restrict__ wih_f, const float* __restrict__ whh_f,
                            const float* __restrict__ wih_b, const float* __restrict__ whh_b,
                            _Float16* __restrict__ Wall) {
  int tid = blockIdx.x * 256 + threadIdx.x;  // 98304 total
  int lane = tid & 63;
  int r = tid >> 6;
  int kt = r % 12; r /= 12;
  int nt = r % 16; r /= 16;
  int ds = r;  // 0..7
  if (ds >= 8) return;
  int dir = ds >> 2, slice = ds & 3;
  const float* wih = dir ? wih_b : wih_f;
  const float* whh = dir ? whh_b : whh_f;
  int gu = nt * 16 + (lane & 15);
  int g = gu >> 6, u = gu & 63;
  int row = g * 256 + slice * 64 + u;
  int kbase = kt * 32 + (lane >> 4) * 8;
  _Float16* dst = Wall + (size_t)tid * 8;
#pragma unroll
  for (int j = 0; j < 8; ++j) {
    int k = kbase + j;
    float v;
    if (k < EMB_) {
      v = wih[row * EMB_ + k];
    } else if (k < EMB_ + 64) {
      v = whh[row * HID_ + slice * 64 + (k - EMB_)];
    } else {
      int jx = k - (EMB_ + 64);
      int rr = jx >> 6;
      int ps = rr + (rr >= slice ? 1 : 0);
      v = whh[row * HID_ + ps * 64 + (jx & 63)];
    }
    dst[j] = (_Float16)(v * LOG2E);
  }
}

__global__ void k_pack_misc(const float* __restrict__ bih_f, const float* __restrict__ bhh_f,
                            const float* __restrict__ bih_b, const float* __restrict__ bhh_b,
                            const float* __restrict__ lin_w, float* __restrict__ bsum,
                            _Float16* __restrict__ linWp) {
  int t = blockIdx.x * 256 + threadIdx.x;
  if (t < 2048) {
    int dir = t >> 10, g = t & 1023;
    bsum[t] = (dir ? (bih_b[g] + bhh_b[g]) : (bih_f[g] + bhh_f[g])) * LOG2E;
  } else if (t < 2048 + 5120) {
    int u = t - 2048;
    int lane = u & 63;
    int r = u >> 6;
    int kt = r % 16, nt = r / 16;
    int n = nt * 16 + (lane & 15);
    int kbase = kt * 32 + (lane >> 4) * 8;
    _Float16* dst = linWp + (size_t)u * 8;
#pragma unroll
    for (int j = 0; j < 8; ++j) dst[j] = (_Float16)lin_w[n * 512 + kbase + j];
  }
}

__global__ void k_dur(const int* __restrict__ x, const float* __restrict__ embed,
                      const float* __restrict__ dp_w, const float* __restrict__ dp_b,
                      int* __restrict__ dur) {
  int gid = blockIdx.x * 256 + threadIdx.x;
  if (gid >= B_ * T_) return;
  const float* er = embed + (size_t)x[gid] * EMB_;
  float d = 0.f;
  for (int e = 0; e < EMB_; ++e) d += er[e] * dp_w[e];
  d += dp_b[0];
  d = fmaxf(d, 0.f);
  dur[gid] = (int)floorf(d) + 1;
}

__global__ void k_scan(const int* __restrict__ dur, int* __restrict__ cum) {
  __shared__ int s[512];
  int b = blockIdx.x, t = threadIdx.x;
  s[t] = dur[b * 512 + t];
  __syncthreads();
  for (int off = 1; off < 512; off <<= 1) {
    int v = (t >= off) ? s[t - off] : 0;
    __syncthreads();
    s[t] += v;
    __syncthreads();
  }
  cum[b * 512 + t] = s[t];
}

__global__ void k_fill(int* __restrict__ p, int n, int v) {
  int gid = blockIdx.x * 256 + threadIdx.x;
  if (gid < n) p[gid] = v;
}

// sentinel-fill mailbox (0xFFFFFFFF = fp16 NaN pair, impossible as real h)
__global__ void k_fill_sent(unsigned int* __restrict__ p, int n4) {
  int gid = blockIdx.x * 256 + threadIdx.x;
  if (gid < n4) ((u32x4*)p)[gid] = u32x4{0xFFFFFFFFu, 0xFFFFFFFFu, 0xFFFFFFFFu, 0xFFFFFFFFu};
}

__global__ void k_scatter(const int* __restrict__ cum, int* __restrict__ idx, int L) {
  int b = blockIdx.x, t = threadIdx.x;
  int c1 = cum[b * 512 + t];
  int c0 = t ? cum[b * 512 + t - 1] : 0;
  for (int p = c0; p < c1; ++p)
    if (p < L) idx[(size_t)b * L + p] = t;
}

__global__ void k_expand(const int* __restrict__ x, const float* __restrict__ embed,
                         const int* __restrict__ idx, _Float16* __restrict__ expb, int L) {
  int gid = blockIdx.x * 256 + threadIdx.x;
  if (gid >= B_ * L * 16) return;
  int ch = gid & 15;
  int rem = gid >> 4;
  int l = rem % L;
  int b = rem / L;
  int ix = idx[(size_t)b * L + l];
  half8 v;
  if (ix < 0) {
#pragma unroll
    for (int j = 0; j < 8; ++j) v[j] = (_Float16)0.f;
  } else {
    const float* er = embed + (size_t)x[b * 512 + ix] * EMB_ + ch * 8;
#pragma unroll
    for (int j = 0; j < 8; ++j) v[j] = (_Float16)er[j];
  }
  *(half8*)(expb + ((size_t)b * L + l) * EMB_ + ch * 8) = v;
}

// 16 worker blocks = 2 dirs x 4 hidden-slices x 2 batch-halves (M=32).
// Two independent 4-block rings per dir (batch halves never interact).
// Exchange = R4-proven agent-scope sentinel mailbox; barriers drain lgkm only.
// Per-unit nonlinearity = 2 trans ops each via exp2/rcp (log2e pre-folded).
__global__ __launch_bounds__(256, 1) void k_rec(
    const _Float16* __restrict__ expb, const _Float16* __restrict__ Wall,
    const float* __restrict__ bsum, _Float16* __restrict__ mail, int L) {
  __shared__ __align__(16) _Float16 Ash[32][392];  // [b-local][ x(128)|own(64)|remote(192)|pad ]
  int tid = threadIdx.x;
  int bh = blockIdx.x & 1;
  int ds = blockIdx.x >> 1;
  int dir = ds >> 2, slice = ds & 3;
  int wv = tid >> 6, lane = tid & 63;
  int c = lane & 15, kg = lane >> 4;
  unsigned int* mail32 = (unsigned int*)mail;
  int rbl = tid >> 3, q = tid & 7;        // consumer: local batch row, word-lane
  int cb = bh * 32 + rbl;                 // global batch row polled
  int s32 = slice * 32;

  for (int i = tid; i < 32 * 392 / 8; i += 256)
    ((half8*)&Ash[0][0])[i] = half8{0, 0, 0, 0, 0, 0, 0, 0};
  float bias[4];
#pragma unroll
  for (int g = 0; g < 4; ++g)
    bias[g] = bsum[dir * 1024 + g * 256 + slice * 64 + wv * 16 + c];
  half8 breg[4][12];
#pragma unroll
  for (int g = 0; g < 4; ++g) {
    int nt = wv + 4 * g;
#pragma unroll
    for (int kt = 0; kt < 12; ++kt)
      breg[g][kt] = *(const half8*)(Wall + (((size_t)(ds * 16 + nt) * 12 + kt) * 64 + lane) * 8);
  }
  float creg[8];
#pragma unroll
  for (int i = 0; i < 8; ++i) creg[i] = 0.f;
  __syncthreads();
  {  // x_0 for this batch-half
    int l0 = dir ? (L - 1) : 0;
#pragma unroll
    for (int r = 0; r < 2; ++r) {
      int f = tid + 256 * r;
      int bl = f >> 4, ch = f & 15;
      *(half8*)&Ash[bl][ch * 8] =
          *(const half8*)(expb + ((size_t)(bh * 32 + bl) * L + l0) * EMB_ + ch * 8);
    }
  }
  __syncthreads();

  for (int s = 0; s < L; ++s) {
    int l_io = dir ? (L - 1 - s) : s;
    // --- p0: issue coalesced poll loads for remote h_{s-1} + x(s+1) prefetch ---
    unsigned int v[12];
    const unsigned int* rp = nullptr;
    if (s > 0) {
      int l_prev = dir ? (L - s) : (s - 1);
      rp = mail32 + ((size_t)(l_prev * 2 + dir) * 64 + cb) * 128;
#pragma unroll
      for (int wd = 0; wd < 12; ++wd) {
        int j32 = wd * 8 + q;
        int jm = j32 + (j32 >= s32 ? 32 : 0);
        v[wd] = __hip_atomic_load(rp + jm, __ATOMIC_RELAXED, __HIP_MEMORY_SCOPE_AGENT);
      }
    }
    half8 xr[2];
    if (s + 1 < L) {
      int l1 = dir ? (L - 2 - s) : (s + 1);
#pragma unroll
      for (int r = 0; r < 2; ++r) {
        int f = tid + 256 * r;
        int bl = f >> 4, ch = f & 15;
        xr[r] = *(const half8*)(expb + ((size_t)(bh * 32 + bl) * L + l1) * EMB_ + ch * 8);
      }
    }
    // --- p1: GEMM-A (x_s + own h_{s-1}), overlaps poll flight ---
    f32x4 acc[2][4];
#pragma unroll
    for (int m = 0; m < 2; ++m)
#pragma unroll
      for (int g = 0; g < 4; ++g) acc[m][g] = f32x4{0.f, 0.f, 0.f, 0.f};
#pragma unroll
    for (int kt = 0; kt < 6; ++kt) {
      half8 a[2];
#pragma unroll
      for (int m = 0; m < 2; ++m) a[m] = *(const half8*)&Ash[m * 16 + c][kt * 32 + kg * 8];
#pragma unroll
      for (int m = 0; m < 2; ++m)
#pragma unroll
        for (int g = 0; g < 4; ++g)
          acc[m][g] = __builtin_amdgcn_mfma_f32_16x16x32_f16(a[m], breg[g][kt], acc[m][g], 0, 0, 0);
    }
    // --- p2: validate polls (adaptive sleep), remote h -> Ash ---
    if (s > 0) {
      int rounds = 0;
      while (true) {
        int miss = 0;
#pragma unroll
        for (int wd = 0; wd < 12; ++wd) miss |= (v[wd] == 0xFFFFFFFFu) ? 1 : 0;
        if (!__any(miss)) break;
        ++rounds;
        if (rounds < 3) {
          __builtin_amdgcn_s_sleep(2);
        } else {
          __builtin_amdgcn_s_sleep(16);
        }
#pragma unroll
        for (int wd = 0; wd < 12; ++wd)
          if (v[wd] == 0xFFFFFFFFu) {
            int j32 = wd * 8 + q;
            int jm = j32 + (j32 >= s32 ? 32 : 0);
            v[wd] = __hip_atomic_load(rp + jm, __ATOMIC_RELAXED, __HIP_MEMORY_SCOPE_AGENT);
          }
      }
      unsigned int* ar = (unsigned int*)&Ash[rbl][0];
#pragma unroll
      for (int wd = 0; wd < 12; ++wd) {
        int j32 = wd * 8 + q;
        int jm = j32 + (j32 >= s32 ? 32 : 0);
        int ps = jm >> 5;
        int rr = ps - (ps > slice ? 1 : 0);
        ar[96 + rr * 32 + (jm & 31)] = v[wd];
      }
    }
    barrier_lds();  // B1
    // --- p3: x(s+1) -> Ash (region free after GEMM-A) ---
    if (s + 1 < L) {
#pragma unroll
      for (int r = 0; r < 2; ++r) {
        int f = tid + 256 * r;
        int bl = f >> 4, ch = f & 15;
        *(half8*)&Ash[bl][ch * 8] = xr[r];
      }
    }
    // --- p4: GEMM-B (remote h) ---
#pragma unroll
    for (int kt = 6; kt < 12; ++kt) {
      half8 a[2];
#pragma unroll
      for (int m = 0; m < 2; ++m) a[m] = *(const half8*)&Ash[m * 16 + c][kt * 32 + kg * 8];
#pragma unroll
      for (int m = 0; m < 2; ++m)
#pragma unroll
        for (int g = 0; g < 4; ++g)
          acc[m][g] = __builtin_amdgcn_mfma_f32_16x16x32_f16(a[m], breg[g][kt], acc[m][g], 0, 0, 0);
    }
    // --- p5: cell update (exp2/rcp raw-HW nonlins; pre-acts log2e-scaled) ---
    _Float16 hv[8];
#pragma unroll
    for (int m = 0; m < 2; ++m)
#pragma unroll
      for (int i = 0; i < 4; ++i) {
        float iv = acc[m][0][i] + bias[0];
        float fv = acc[m][1][i] + bias[1];
        float gv = acc[m][2][i] + bias[2];
        float ov = acc[m][3][i] + bias[3];
        float cc = sig2(fv) * creg[m * 4 + i] + sig2(iv) * tanh2(2.f * gv);
        float hh = sig2(ov) * tanh2(2.f * LOG2E * cc);
        creg[m * 4 + i] = cc;
        hv[m * 4 + i] = (_Float16)hh;
      }
    // --- p6: publish h_s (pair-packed u32, relaxed agent, never drained) ---
#pragma unroll
    for (int m = 0; m < 2; ++m)
#pragma unroll
      for (int i = 0; i < 4; ++i) {
        int id = m * 4 + i;
        unsigned int mine = (unsigned int)__builtin_bit_cast(unsigned short, hv[id]);
        unsigned int part = (unsigned int)(unsigned)__shfl_xor((int)mine, 1, 64);
        unsigned int word = (c & 1) ? ((mine << 16) | part) : (mine | (part << 16));
        if (((c & 1) == 0) == (m < 1)) {
          int b = bh * 32 + m * 16 + kg * 4 + i;
          __hip_atomic_store(
              mail32 + ((size_t)(l_io * 2 + dir) * 64 + b) * 128 + slice * 32 + wv * 8 + (c >> 1),
              word, __ATOMIC_RELAXED, __HIP_MEMORY_SCOPE_AGENT);
        }
      }
    // --- p7: own h -> Ash ---
#pragma unroll
    for (int m = 0; m < 2; ++m)
#pragma unroll
      for (int i = 0; i < 4; ++i)
        Ash[m * 16 + kg * 4 + i][EMB_ + wv * 16 + c] = hv[m * 4 + i];
    barrier_lds();  // B2
  }
}

// out[r,:80] = h(b,l) @ lin_w.T + lin_b, reading from mailbox [l][dir][b][u]
__global__ __launch_bounds__(256) void k_linear(
    const _Float16* __restrict__ mail, const _Float16* __restrict__ linWp,
    const float* __restrict__ lin_b, float* __restrict__ out, int L) {
  int tid = threadIdx.x;
  int wv = tid >> 6, lane = tid & 63;
  int arow = lane & 15, kgrp = lane >> 4;
  int mt = blockIdx.x * 4 + wv;  // < 4L
  int r0 = mt * 16 + arow;       // A-row = b*L + l
  int b = r0 / L, l = r0 - b * L;
  const _Float16* base0 = mail + ((size_t)(l * 2 + 0) * 64 + b) * 256 + kgrp * 8;
  const _Float16* base1 = mail + ((size_t)(l * 2 + 1) * 64 + b) * 256 + kgrp * 8;
  half8 a[16];
#pragma unroll
  for (int kt = 0; kt < 8; ++kt) a[kt] = *(const half8*)(base0 + kt * 32);
#pragma unroll
  for (int kt = 8; kt < 16; ++kt) a[kt] = *(const half8*)(base1 + (kt - 8) * 32);
#pragma unroll
  for (int nt = 0; nt < 5; ++nt) {
    f32x4 acc = {0.f, 0.f, 0.f, 0.f};
    const half8* Bp = (const half8*)(linWp + (size_t)nt * 16 * 512) + lane;
#pragma unroll
    for (int kt = 0; kt < 16; ++kt)
      acc = __builtin_amdgcn_mfma_f32_16x16x32_f16(a[kt], Bp[kt * 64], acc, 0, 0, 0);
    int col = nt * 16 + arow;
    float bb = lin_b[col];
#pragma unroll
    for (int i = 0; i < 4; ++i)
      out[(size_t)(mt * 16 + kgrp * 4 + i) * MEL_ + col] = acc[i] + bb;
  }
}

extern "C" void kernel_launch(void* const* d_in, const int* in_sizes, int n_in,
                              void* d_out, int out_size, void* d_ws, size_t ws_size,
                              hipStream_t stream) {
  const int* x = (const int*)d_in[0];
  const float* embed = (const float*)d_in[1];
  const float* dp_w = (const float*)d_in[2];
  const float* dp_b = (const float*)d_in[3];
  const float* wih_f = (const float*)d_in[4];
  const float* whh_f = (const float*)d_in[5];
  const float* bih_f = (const float*)d_in[6];
  const float* bhh_f = (const float*)d_in[7];
  const float* wih_b = (const float*)d_in[8];
  const float* whh_b = (const float*)d_in[9];
  const float* bih_b = (const float*)d_in[10];
  const float* bhh_b = (const float*)d_in[11];
  const float* lin_w = (const float*)d_in[12];
  const float* lin_b = (const float*)d_in[13];
  float* out = (float*)d_out;
  (void)in_sizes; (void)n_in; (void)ws_size;

  int L = out_size / (B_ * MEL_);
  char* base = (char*)d_ws;
  size_t o = 0;
  auto take = [&](size_t bytes) {
    void* p = base + o;
    o = (o + bytes + 255) & ~(size_t)255;
    return p;
  };
  int* dur = (int*)take((size_t)B_ * T_ * 4);
  int* cum = (int*)take((size_t)B_ * T_ * 4);
  int* idx = (int*)take((size_t)B_ * L * 4);
  _Float16* Wall = (_Float16*)take((size_t)8 * 16 * 12 * 512 * 2);
  float* bsum = (float*)take(2048 * 4);
  _Float16* linWp = (_Float16*)take((size_t)5 * 16 * 512 * 2);
  _Float16* expb = (_Float16*)take((size_t)B_ * L * EMB_ * 2);
  _Float16* mail = (_Float16*)take((size_t)L * 2 * 64 * 256 * 2);

  hipLaunchKernelGGL(k_pack_wall, dim3(384), dim3(256), 0, stream, wih_f, whh_f, wih_b, whh_b, Wall);
  hipLaunchKernelGGL(k_pack_misc, dim3(28), dim3(256), 0, stream, bih_f, bhh_f, bih_b, bhh_b,
                     lin_w, bsum, linWp);
  hipLaunchKernelGGL(k_dur, dim3(128), dim3(256), 0, stream, x, embed, dp_w, dp_b, dur);
  hipLaunchKernelGGL(k_scan, dim3(64), dim3(512), 0, stream, dur, cum);
  hipLaunchKernelGGL(k_fill, dim3((B_ * L + 255) / 256), dim3(256), 0, stream, idx, B_ * L, -1);
  {
    int n4 = L * 4096;  // mailbox u32 count / 4
    hipLaunchKernelGGL(k_fill_sent, dim3((n4 + 255) / 256), dim3(256), 0, stream,
                       (unsigned int*)mail, n4);
  }
  hipLaunchKernelGGL(k_scatter, dim3(64), dim3(512), 0, stream, cum, idx, L);
  hipLaunchKernelGGL(k_expand, dim3((B_ * L * 16 + 255) / 256), dim3(256), 0, stream,
                     x, embed, idx, expb, L);
  hipLaunchKernelGGL(k_rec, dim3(16), dim3(256), 0, stream, expb, Wall, bsum, mail, L);
  hipLaunchKernelGGL(k_linear, dim3(L), dim3(256), 0, stream, mail, linWp, lin_b, out, L);
}

// Round 9
// 1096.042 us; speedup vs baseline: 12.9969x; 1.7579x over previous
//
#include <hip/hip_runtime.h>
#include <hip/hip_fp16.h>

#define B_ 64
#define T_ 512
#define EMB_ 128
#define HID_ 256
#define MEL_ 80
#define LOG2E 1.44269504f

typedef __attribute__((ext_vector_type(8))) _Float16 half8;
typedef __attribute__((ext_vector_type(4))) float f32x4;
typedef __attribute__((ext_vector_type(4))) unsigned int u32x4;

// raw HW transcendentals (~1e-6 rel err, far below fp16 h quantization).
__device__ __forceinline__ float exp2_asm(float x) {
  float r;
  asm("v_exp_f32 %0, %1" : "=v"(r) : "v"(x));
  return r;
}
__device__ __forceinline__ float rcp_asm(float x) {
  float r;
  asm("v_rcp_f32 %0, %1" : "=v"(r) : "v"(x));
  return r;
}
// x' is log2e-prescaled (folded into weights+bias)
__device__ __forceinline__ float sig2(float xp) { return rcp_asm(1.f + exp2_asm(-xp)); }
// pass x2 = 2*log2e*y ; tanh(y) = 1 - 2/(1+e^{2y})
__device__ __forceinline__ float tanh2(float x2) { return 1.f - 2.f * rcp_asm(1.f + exp2_asm(x2)); }

// Barrier that drains ONLY LDS (lgkmcnt), not vmcnt: publish stores and poll
// loads stay in flight across it. All cross-wave data handoff here is LDS.
__device__ __forceinline__ void barrier_lds() {
  __builtin_amdgcn_sched_barrier(0);
  asm volatile("s_waitcnt lgkmcnt(0)" ::: "memory");
  __builtin_amdgcn_s_barrier();
  __builtin_amdgcn_sched_barrier(0);
}

// Pack W=[wih|whh] (per dir 1024x384) into MFMA B-frags with PER-BLOCK K order:
// [ x(0..127) | own-slice h(64) | remote slices ascending (192) ]. Rows in
// gu-order (wave wv owns units wv*16.., gates via nt=wv+4g). Weights are
// PRE-SCALED by log2e so gate pre-acts arrive ready for exp2-based nonlins.
// Wall[((ds*16+nt)*12+kt)*64 + lane][8]
__global__ void k_pack_wall(const float* __restrict__ wih_f, const float* __restrict__ whh_f,
                            const float* __restrict__ wih_b, const float* __restrict__ whh_b,
                            _Float16* __restrict__ Wall) {
  int tid = blockIdx.x * 256 + threadIdx.x;  // 98304 total
  int lane = tid & 63;
  int r = tid >> 6;
  int kt = r % 12; r /= 12;
  int nt = r % 16; r /= 16;
  int ds = r;  // 0..7
  if (ds >= 8) return;
  int dir = ds >> 2, slice = ds & 3;
  const float* wih = dir ? wih_b : wih_f;
  const float* whh = dir ? whh_b : whh_f;
  int gu = nt * 16 + (lane & 15);
  int g = gu >> 6, u = gu & 63;
  int row = g * 256 + slice * 64 + u;
  int kbase = kt * 32 + (lane >> 4) * 8;
  _Float16* dst = Wall + (size_t)tid * 8;
#pragma unroll
  for (int j = 0; j < 8; ++j) {
    int k = kbase + j;
    float v;
    if (k < EMB_) {
      v = wih[row * EMB_ + k];
    } else if (k < EMB_ + 64) {
      v = whh[row * HID_ + slice * 64 + (k - EMB_)];
    } else {
      int jx = k - (EMB_ + 64);
      int rr = jx >> 6;
      int ps = rr + (rr >= slice ? 1 : 0);
      v = whh[row * HID_ + ps * 64 + (jx & 63)];
    }
    dst[j] = (_Float16)(v * LOG2E);
  }
}

__global__ void k_pack_misc(const float* __restrict__ bih_f, const float* __restrict__ bhh_f,
                            const float* __restrict__ bih_b, const float* __restrict__ bhh_b,
                            const float* __restrict__ lin_w, float* __restrict__ bsum,
                            _Float16* __restrict__ linWp) {
  int t = blockIdx.x * 256 + threadIdx.x;
  if (t < 2048) {
    int dir = t >> 10, g = t & 1023;
    bsum[t] = (dir ? (bih_b[g] + bhh_b[g]) : (bih_f[g] + bhh_f[g])) * LOG2E;
  } else if (t < 2048 + 5120) {
    int u = t - 2048;
    int lane = u & 63;
    int r = u >> 6;
    int kt = r % 16, nt = r / 16;
    int n = nt * 16 + (lane & 15);
    int kbase = kt * 32 + (lane >> 4) * 8;
    _Float16* dst = linWp + (size_t)u * 8;
#pragma unroll
    for (int j = 0; j < 8; ++j) dst[j] = (_Float16)lin_w[n * 512 + kbase + j];
  }
}

__global__ void k_dur(const int* __restrict__ x, const float* __restrict__ embed,
                      const float* __restrict__ dp_w, const float* __restrict__ dp_b,
                      int* __restrict__ dur) {
  int gid = blockIdx.x * 256 + threadIdx.x;
  if (gid >= B_ * T_) return;
  const float* er = embed + (size_t)x[gid] * EMB_;
  float d = 0.f;
  for (int e = 0; e < EMB_; ++e) d += er[e] * dp_w[e];
  d += dp_b[0];
  d = fmaxf(d, 0.f);
  dur[gid] = (int)floorf(d) + 1;
}

__global__ void k_scan(const int* __restrict__ dur, int* __restrict__ cum) {
  __shared__ int s[512];
  int b = blockIdx.x, t = threadIdx.x;
  s[t] = dur[b * 512 + t];
  __syncthreads();
  for (int off = 1; off < 512; off <<= 1) {
    int v = (t >= off) ? s[t - off] : 0;
    __syncthreads();
    s[t] += v;
    __syncthreads();
  }
  cum[b * 512 + t] = s[t];
}

__global__ void k_fill(int* __restrict__ p, int n, int v) {
  int gid = blockIdx.x * 256 + threadIdx.x;
  if (gid < n) p[gid] = v;
}

// sentinel-fill mailbox (0xFFFFFFFF = fp16 NaN pair, impossible as real h)
__global__ void k_fill_sent(unsigned int* __restrict__ p, int n4) {
  int gid = blockIdx.x * 256 + threadIdx.x;
  if (gid < n4) ((u32x4*)p)[gid] = u32x4{0xFFFFFFFFu, 0xFFFFFFFFu, 0xFFFFFFFFu, 0xFFFFFFFFu};
}

__global__ void k_scatter(const int* __restrict__ cum, int* __restrict__ idx, int L) {
  int b = blockIdx.x, t = threadIdx.x;
  int c1 = cum[b * 512 + t];
  int c0 = t ? cum[b * 512 + t - 1] : 0;
  for (int p = c0; p < c1; ++p)
    if (p < L) idx[(size_t)b * L + p] = t;
}

__global__ void k_expand(const int* __restrict__ x, const float* __restrict__ embed,
                         const int* __restrict__ idx, _Float16* __restrict__ expb, int L) {
  int gid = blockIdx.x * 256 + threadIdx.x;
  if (gid >= B_ * L * 16) return;
  int ch = gid & 15;
  int rem = gid >> 4;
  int l = rem % L;
  int b = rem / L;
  int ix = idx[(size_t)b * L + l];
  half8 v;
  if (ix < 0) {
#pragma unroll
    for (int j = 0; j < 8; ++j) v[j] = (_Float16)0.f;
  } else {
    const float* er = embed + (size_t)x[b * 512 + ix] * EMB_ + ch * 8;
#pragma unroll
    for (int j = 0; j < 8; ++j) v[j] = (_Float16)er[j];
  }
  *(half8*)(expb + ((size_t)b * L + l) * EMB_ + ch * 8) = v;
}

// 32 worker blocks = 2 dirs x 4 hidden-slices x 4 batch-quarters (M=16).
// Four independent 4-block rings per dir. Exchange = R4-proven agent-scope
// sentinel mailbox; barriers drain lgkm only. Weights resident in regs;
// nonlins = exp2/rcp (log2e pre-folded).
__global__ __launch_bounds__(256, 1) void k_rec(
    const _Float16* __restrict__ expb, const _Float16* __restrict__ Wall,
    const float* __restrict__ bsum, _Float16* __restrict__ mail, int L) {
  __shared__ __align__(16) _Float16 Ash[16][392];  // [b-local][ x(128)|own(64)|remote(192)|pad ]
  int tid = threadIdx.x;
  int bq = blockIdx.x & 3;
  int ds = blockIdx.x >> 2;
  int dir = ds >> 2, slice = ds & 3;
  int wv = tid >> 6, lane = tid & 63;
  int c = lane & 15, kg = lane >> 4;
  unsigned int* mail32 = (unsigned int*)mail;
  int rbl = tid >> 4, q = tid & 15;  // consumer: local batch row, word-lane
  int cb = bq * 16 + rbl;            // global batch row polled
  int s32 = slice * 32;

  for (int i = tid; i < 16 * 392 / 8; i += 256)
    ((half8*)&Ash[0][0])[i] = half8{0, 0, 0, 0, 0, 0, 0, 0};
  float bias[4];
#pragma unroll
  for (int g = 0; g < 4; ++g)
    bias[g] = bsum[dir * 1024 + g * 256 + slice * 64 + wv * 16 + c];
  half8 breg[4][12];
#pragma unroll
  for (int g = 0; g < 4; ++g) {
    int nt = wv + 4 * g;
#pragma unroll
    for (int kt = 0; kt < 12; ++kt)
      breg[g][kt] = *(const half8*)(Wall + (((size_t)(ds * 16 + nt) * 12 + kt) * 64 + lane) * 8);
  }
  float creg[4];
#pragma unroll
  for (int i = 0; i < 4; ++i) creg[i] = 0.f;
  __syncthreads();
  {  // x_0 for this batch-quarter (16 batches x 16 ch = 256 loads)
    int l0 = dir ? (L - 1) : 0;
    int bl = tid >> 4, ch = tid & 15;
    *(half8*)&Ash[bl][ch * 8] =
        *(const half8*)(expb + ((size_t)(bq * 16 + bl) * L + l0) * EMB_ + ch * 8);
  }
  __syncthreads();

  for (int s = 0; s < L; ++s) {
    int l_io = dir ? (L - 1 - s) : s;
    // --- p0: issue coalesced poll loads for remote h_{s-1} + x(s+1) prefetch ---
    unsigned int v[6];
    const unsigned int* rp = nullptr;
    if (s > 0) {
      int l_prev = dir ? (L - s) : (s - 1);
      rp = mail32 + ((size_t)(l_prev * 2 + dir) * 64 + cb) * 128;
#pragma unroll
      for (int wd = 0; wd < 6; ++wd) {
        int j32 = wd * 16 + q;
        int jm = j32 + (j32 >= s32 ? 32 : 0);
        v[wd] = __hip_atomic_load(rp + jm, __ATOMIC_RELAXED, __HIP_MEMORY_SCOPE_AGENT);
      }
    }
    half8 xr;
    if (s + 1 < L) {
      int l1 = dir ? (L - 2 - s) : (s + 1);
      int bl = tid >> 4, ch = tid & 15;
      xr = *(const half8*)(expb + ((size_t)(bq * 16 + bl) * L + l1) * EMB_ + ch * 8);
    }
    // --- p1: GEMM-A (x_s + own h_{s-1}), overlaps poll flight ---
    f32x4 acc[4];
#pragma unroll
    for (int g = 0; g < 4; ++g) acc[g] = f32x4{0.f, 0.f, 0.f, 0.f};
#pragma unroll
    for (int kt = 0; kt < 6; ++kt) {
      half8 a = *(const half8*)&Ash[c][kt * 32 + kg * 8];
#pragma unroll
      for (int g = 0; g < 4; ++g)
        acc[g] = __builtin_amdgcn_mfma_f32_16x16x32_f16(a, breg[g][kt], acc[g], 0, 0, 0);
    }
    // --- p2: validate polls (adaptive sleep), remote h -> Ash ---
    if (s > 0) {
      int rounds = 0;
      while (true) {
        int miss = 0;
#pragma unroll
        for (int wd = 0; wd < 6; ++wd) miss |= (v[wd] == 0xFFFFFFFFu) ? 1 : 0;
        if (!__any(miss)) break;
        ++rounds;
        if (rounds < 4) {
          __builtin_amdgcn_s_sleep(2);
        } else {
          __builtin_amdgcn_s_sleep(8);
        }
#pragma unroll
        for (int wd = 0; wd < 6; ++wd)
          if (v[wd] == 0xFFFFFFFFu) {
            int j32 = wd * 16 + q;
            int jm = j32 + (j32 >= s32 ? 32 : 0);
            v[wd] = __hip_atomic_load(rp + jm, __ATOMIC_RELAXED, __HIP_MEMORY_SCOPE_AGENT);
          }
      }
      unsigned int* ar = (unsigned int*)&Ash[rbl][0];
#pragma unroll
      for (int wd = 0; wd < 6; ++wd) {
        int j32 = wd * 16 + q;
        int jm = j32 + (j32 >= s32 ? 32 : 0);
        int ps = jm >> 5;
        int rr = ps - (ps > slice ? 1 : 0);
        ar[96 + rr * 32 + (jm & 31)] = v[wd];
      }
    }
    barrier_lds();  // B1
    // --- p3: x(s+1) -> Ash (region free after GEMM-A) ---
    if (s + 1 < L) {
      int bl = tid >> 4, ch = tid & 15;
      *(half8*)&Ash[bl][ch * 8] = xr;
    }
    // --- p4: GEMM-B (remote h) ---
#pragma unroll
    for (int kt = 6; kt < 12; ++kt) {
      half8 a = *(const half8*)&Ash[c][kt * 32 + kg * 8];
#pragma unroll
      for (int g = 0; g < 4; ++g)
        acc[g] = __builtin_amdgcn_mfma_f32_16x16x32_f16(a, breg[g][kt], acc[g], 0, 0, 0);
    }
    // --- p5: cell update (exp2/rcp raw-HW nonlins; pre-acts log2e-scaled) ---
    _Float16 hv[4];
#pragma unroll
    for (int i = 0; i < 4; ++i) {
      float iv = acc[0][i] + bias[0];
      float fv = acc[1][i] + bias[1];
      float gv = acc[2][i] + bias[2];
      float ov = acc[3][i] + bias[3];
      float cc = sig2(fv) * creg[i] + sig2(iv) * tanh2(2.f * gv);
      float hh = sig2(ov) * tanh2(2.f * LOG2E * cc);
      creg[i] = cc;
      hv[i] = (_Float16)hh;
    }
    // --- p6: publish h_s (pair-packed u32, relaxed agent, never drained) ---
#pragma unroll
    for (int i = 0; i < 4; ++i) {
      unsigned int mine = (unsigned int)__builtin_bit_cast(unsigned short, hv[i]);
      unsigned int part = (unsigned int)(unsigned)__shfl_xor((int)mine, 1, 64);
      unsigned int word = mine | (part << 16);
      if ((c & 1) == 0) {
        int b = bq * 16 + kg * 4 + i;
        __hip_atomic_store(
            mail32 + ((size_t)(l_io * 2 + dir) * 64 + b) * 128 + slice * 32 + wv * 8 + (c >> 1),
            word, __ATOMIC_RELAXED, __HIP_MEMORY_SCOPE_AGENT);
      }
    }
    // --- p7: own h -> Ash ---
#pragma unroll
    for (int i = 0; i < 4; ++i)
      Ash[kg * 4 + i][EMB_ + wv * 16 + c] = hv[i];
    barrier_lds();  // B2
  }
}

// out[r,:80] = h(b,l) @ lin_w.T + lin_b, reading from mailbox [l][dir][b][u]
__global__ __launch_bounds__(256) void k_linear(
    const _Float16* __restrict__ mail, const _Float16* __restrict__ linWp,
    const float* __restrict__ lin_b, float* __restrict__ out, int L) {
  int tid = threadIdx.x;
  int wv = tid >> 6, lane = tid & 63;
  int arow = lane & 15, kgrp = lane >> 4;
  int mt = blockIdx.x * 4 + wv;  // < 4L
  int r0 = mt * 16 + arow;       // A-row = b*L + l
  int b = r0 / L, l = r0 - b * L;
  const _Float16* base0 = mail + ((size_t)(l * 2 + 0) * 64 + b) * 256 + kgrp * 8;
  const _Float16* base1 = mail + ((size_t)(l * 2 + 1) * 64 + b) * 256 + kgrp * 8;
  half8 a[16];
#pragma unroll
  for (int kt = 0; kt < 8; ++kt) a[kt] = *(const half8*)(base0 + kt * 32);
#pragma unroll
  for (int kt = 8; kt < 16; ++kt) a[kt] = *(const half8*)(base1 + (kt - 8) * 32);
#pragma unroll
  for (int nt = 0; nt < 5; ++nt) {
    f32x4 acc = {0.f, 0.f, 0.f, 0.f};
    const half8* Bp = (const half8*)(linWp + (size_t)nt * 16 * 512) + lane;
#pragma unroll
    for (int kt = 0; kt < 16; ++kt)
      acc = __builtin_amdgcn_mfma_f32_16x16x32_f16(a[kt], Bp[kt * 64], acc, 0, 0, 0);
    int col = nt * 16 + arow;
    float bb = lin_b[col];
#pragma unroll
    for (int i = 0; i < 4; ++i)
      out[(size_t)(mt * 16 + kgrp * 4 + i) * MEL_ + col] = acc[i] + bb;
  }
}

extern "C" void kernel_launch(void* const* d_in, const int* in_sizes, int n_in,
                              void* d_out, int out_size, void* d_ws, size_t ws_size,
                              hipStream_t stream) {
  const int* x = (const int*)d_in[0];
  const float* embed = (const float*)d_in[1];
  const float* dp_w = (const float*)d_in[2];
  const float* dp_b = (const float*)d_in[3];
  const float* wih_f = (const float*)d_in[4];
  const float* whh_f = (const float*)d_in[5];
  const float* bih_f = (const float*)d_in[6];
  const float* bhh_f = (const float*)d_in[7];
  const float* wih_b = (const float*)d_in[8];
  const float* whh_b = (const float*)d_in[9];
  const float* bih_b = (const float*)d_in[10];
  const float* bhh_b = (const float*)d_in[11];
  const float* lin_w = (const float*)d_in[12];
  const float* lin_b = (const float*)d_in[13];
  float* out = (float*)d_out;
  (void)in_sizes; (void)n_in; (void)ws_size;

  int L = out_size / (B_ * MEL_);
  char* base = (char*)d_ws;
  size_t o = 0;
  auto take = [&](size_t bytes) {
    void* p = base + o;
    o = (o + bytes + 255) & ~(size_t)255;
    return p;
  };
  int* dur = (int*)take((size_t)B_ * T_ * 4);
  int* cum = (int*)take((size_t)B_ * T_ * 4);
  int* idx = (int*)take((size_t)B_ * L * 4);
  _Float16* Wall = (_Float16*)take((size_t)8 * 16 * 12 * 512 * 2);
  float* bsum = (float*)take(2048 * 4);
  _Float16* linWp = (_Float16*)take((size_t)5 * 16 * 512 * 2);
  _Float16* expb = (_Float16*)take((size_t)B_ * L * EMB_ * 2);
  _Float16* mail = (_Float16*)take((size_t)L * 2 * 64 * 256 * 2);

  hipLaunchKernelGGL(k_pack_wall, dim3(384), dim3(256), 0, stream, wih_f, whh_f, wih_b, whh_b, Wall);
  hipLaunchKernelGGL(k_pack_misc, dim3(28), dim3(256), 0, stream, bih_f, bhh_f, bih_b, bhh_b,
                     lin_w, bsum, linWp);
  hipLaunchKernelGGL(k_dur, dim3(128), dim3(256), 0, stream, x, embed, dp_w, dp_b, dur);
  hipLaunchKernelGGL(k_scan, dim3(64), dim3(512), 0, stream, dur, cum);
  hipLaunchKernelGGL(k_fill, dim3((B_ * L + 255) / 256), dim3(256), 0, stream, idx, B_ * L, -1);
  {
    int n4 = L * 4096;  // mailbox u32 count / 4
    hipLaunchKernelGGL(k_fill_sent, dim3((n4 + 255) / 256), dim3(256), 0, stream,
                       (unsigned int*)mail, n4);
  }
  hipLaunchKernelGGL(k_scatter, dim3(64), dim3(512), 0, stream, cum, idx, L);
  hipLaunchKernelGGL(k_expand, dim3((B_ * L * 16 + 255) / 256), dim3(256), 0, stream,
                     x, embed, idx, expb, L);
  hipLaunchKernelGGL(k_rec, dim3(32), dim3(256), 0, stream, expb, Wall, bsum, mail, L);
  hipLaunchKernelGGL(k_linear, dim3(L), dim3(256), 0, stream, mail, linWp, lin_b, out, L);
}

// Round 10
// 971.168 us; speedup vs baseline: 14.6681x; 1.1286x over previous
//
#include <hip/hip_runtime.h>
#include <hip/hip_fp16.h>

#define B_ 64
#define T_ 512
#define EMB_ 128
#define HID_ 256
#define MEL_ 80
#define LOG2E 1.44269504f

typedef __attribute__((ext_vector_type(8))) _Float16 half8;
typedef __attribute__((ext_vector_type(4))) float f32x4;
typedef __attribute__((ext_vector_type(4))) unsigned int u32x4;

// raw HW transcendentals (~1e-6 rel err, far below fp16 h quantization).
__device__ __forceinline__ float exp2_asm(float x) {
  float r;
  asm("v_exp_f32 %0, %1" : "=v"(r) : "v"(x));
  return r;
}
__device__ __forceinline__ float rcp_asm(float x) {
  float r;
  asm("v_rcp_f32 %0, %1" : "=v"(r) : "v"(x));
  return r;
}
// x' is log2e-prescaled (folded into weights+bias)
__device__ __forceinline__ float sig2(float xp) { return rcp_asm(1.f + exp2_asm(-xp)); }
// pass x2 = 2*log2e*y ; tanh(y) = 1 - 2/(1+e^{2y})
__device__ __forceinline__ float tanh2(float x2) { return 1.f - 2.f * rcp_asm(1.f + exp2_asm(x2)); }

// Barrier that drains ONLY LDS (lgkmcnt), not vmcnt: publish stores and poll
// loads stay in flight across it. All cross-wave data handoff here is LDS.
__device__ __forceinline__ void barrier_lds() {
  __builtin_amdgcn_sched_barrier(0);
  asm volatile("s_waitcnt lgkmcnt(0)" ::: "memory");
  __builtin_amdgcn_s_barrier();
  __builtin_amdgcn_sched_barrier(0);
}

// Pack W=[wih|whh] (per dir 1024x384) into MFMA B-frags with PER-BLOCK K order:
// [ x(0..127) | own-slice h(64) | remote slices ascending (192) ]. Rows in
// gu-order (wave wv owns units wv*16.., gates via nt=wv+4g). Weights are
// PRE-SCALED by log2e so gate pre-acts arrive ready for exp2-based nonlins.
// Wall[((ds*16+nt)*12+kt)*64 + lane][8]
__global__ void k_pack_wall(const float* __restrict__ wih_f, const float* __restrict__ whh_f,
                            const float* __restrict__ wih_b, const float* __restrict__ whh_b,
                            _Float16* __restrict__ Wall) {
  int tid = blockIdx.x * 256 + threadIdx.x;  // 98304 total
  int lane = tid & 63;
  int r = tid >> 6;
  int kt = r % 12; r /= 12;
  int nt = r % 16; r /= 16;
  int ds = r;  // 0..7
  if (ds >= 8) return;
  int dir = ds >> 2, slice = ds & 3;
  const float* wih = dir ? wih_b : wih_f;
  const float* whh = dir ? whh_b : whh_f;
  int gu = nt * 16 + (lane & 15);
  int g = gu >> 6, u = gu & 63;
  int row = g * 256 + slice * 64 + u;
  int kbase = kt * 32 + (lane >> 4) * 8;
  _Float16* dst = Wall + (size_t)tid * 8;
#pragma unroll
  for (int j = 0; j < 8; ++j) {
    int k = kbase + j;
    float v;
    if (k < EMB_) {
      v = wih[row * EMB_ + k];
    } else if (k < EMB_ + 64) {
      v = whh[row * HID_ + slice * 64 + (k - EMB_)];
    } else {
      int jx = k - (EMB_ + 64);
      int rr = jx >> 6;
      int ps = rr + (rr >= slice ? 1 : 0);
      v = whh[row * HID_ + ps * 64 + (jx & 63)];
    }
    dst[j] = (_Float16)(v * LOG2E);
  }
}

__global__ void k_pack_misc(const float* __restrict__ bih_f, const float* __restrict__ bhh_f,
                            const float* __restrict__ bih_b, const float* __restrict__ bhh_b,
                            const float* __restrict__ lin_w, float* __restrict__ bsum,
                            _Float16* __restrict__ linWp) {
  int t = blockIdx.x * 256 + threadIdx.x;
  if (t < 2048) {
    int dir = t >> 10, g = t & 1023;
    bsum[t] = (dir ? (bih_b[g] + bhh_b[g]) : (bih_f[g] + bhh_f[g])) * LOG2E;
  } else if (t < 2048 + 5120) {
    int u = t - 2048;
    int lane = u & 63;
    int r = u >> 6;
    int kt = r % 16, nt = r / 16;
    int n = nt * 16 + (lane & 15);
    int kbase = kt * 32 + (lane >> 4) * 8;
    _Float16* dst = linWp + (size_t)u * 8;
#pragma unroll
    for (int j = 0; j < 8; ++j) dst[j] = (_Float16)lin_w[n * 512 + kbase + j];
  }
}

__global__ void k_dur(const int* __restrict__ x, const float* __restrict__ embed,
                      const float* __restrict__ dp_w, const float* __restrict__ dp_b,
                      int* __restrict__ dur) {
  int gid = blockIdx.x * 256 + threadIdx.x;
  if (gid >= B_ * T_) return;
  const float* er = embed + (size_t)x[gid] * EMB_;
  float d = 0.f;
  for (int e = 0; e < EMB_; ++e) d += er[e] * dp_w[e];
  d += dp_b[0];
  d = fmaxf(d, 0.f);
  dur[gid] = (int)floorf(d) + 1;
}

__global__ void k_scan(const int* __restrict__ dur, int* __restrict__ cum) {
  __shared__ int s[512];
  int b = blockIdx.x, t = threadIdx.x;
  s[t] = dur[b * 512 + t];
  __syncthreads();
  for (int off = 1; off < 512; off <<= 1) {
    int v = (t >= off) ? s[t - off] : 0;
    __syncthreads();
    s[t] += v;
    __syncthreads();
  }
  cum[b * 512 + t] = s[t];
}

__global__ void k_fill(int* __restrict__ p, int n, int v) {
  int gid = blockIdx.x * 256 + threadIdx.x;
  if (gid < n) p[gid] = v;
}

// sentinel-fill mailbox (0xFFFFFFFF = fp16 NaN pair, impossible as real h)
__global__ void k_fill_sent(unsigned int* __restrict__ p, int n4) {
  int gid = blockIdx.x * 256 + threadIdx.x;
  if (gid < n4) ((u32x4*)p)[gid] = u32x4{0xFFFFFFFFu, 0xFFFFFFFFu, 0xFFFFFFFFu, 0xFFFFFFFFu};
}

__global__ void k_scatter(const int* __restrict__ cum, int* __restrict__ idx, int L) {
  int b = blockIdx.x, t = threadIdx.x;
  int c1 = cum[b * 512 + t];
  int c0 = t ? cum[b * 512 + t - 1] : 0;
  for (int p = c0; p < c1; ++p)
    if (p < L) idx[(size_t)b * L + p] = t;
}

__global__ void k_expand(const int* __restrict__ x, const float* __restrict__ embed,
                         const int* __restrict__ idx, _Float16* __restrict__ expb, int L) {
  int gid = blockIdx.x * 256 + threadIdx.x;
  if (gid >= B_ * L * 16) return;
  int ch = gid & 15;
  int rem = gid >> 4;
  int l = rem % L;
  int b = rem / L;
  int ix = idx[(size_t)b * L + l];
  half8 v;
  if (ix < 0) {
#pragma unroll
    for (int j = 0; j < 8; ++j) v[j] = (_Float16)0.f;
  } else {
    const float* er = embed + (size_t)x[b * 512 + ix] * EMB_ + ch * 8;
#pragma unroll
    for (int j = 0; j < 8; ++j) v[j] = (_Float16)er[j];
  }
  *(half8*)(expb + ((size_t)b * L + l) * EMB_ + ch * 8) = v;
}

// 32 worker blocks = 2 dirs x 4 hidden-slices x 4 batch-quarters (M=16).
// Four independent 4-block rings per dir. Exchange = agent-scope sentinel
// mailbox with PIPELINED DOUBLE-POLL: set-1 issued at step top, set-2 issued
// after GEMM-A before validating set-1 (one extra RT already in flight when
// set-1 misses). Barriers drain lgkm only. Weights resident in regs; nonlins
// = exp2/rcp (log2e pre-folded).
__global__ __launch_bounds__(256, 1) void k_rec(
    const _Float16* __restrict__ expb, const _Float16* __restrict__ Wall,
    const float* __restrict__ bsum, _Float16* __restrict__ mail, int L) {
  __shared__ __align__(16) _Float16 Ash[16][392];  // [b-local][ x(128)|own(64)|remote(192)|pad ]
  int tid = threadIdx.x;
  int bq = blockIdx.x & 3;
  int ds = blockIdx.x >> 2;
  int dir = ds >> 2, slice = ds & 3;
  int wv = tid >> 6, lane = tid & 63;
  int c = lane & 15, kg = lane >> 4;
  unsigned int* mail32 = (unsigned int*)mail;
  int rbl = tid >> 4, q = tid & 15;  // consumer: local batch row, word-lane
  int cb = bq * 16 + rbl;            // global batch row polled
  int s32 = slice * 32;
  // precomputed mailbox word offsets (canonical j32 -> skip own slice)
  int jm_[6];
#pragma unroll
  for (int wd = 0; wd < 6; ++wd) {
    int j32 = wd * 16 + q;
    jm_[wd] = j32 + (j32 >= s32 ? 32 : 0);
  }

  for (int i = tid; i < 16 * 392 / 8; i += 256)
    ((half8*)&Ash[0][0])[i] = half8{0, 0, 0, 0, 0, 0, 0, 0};
  float bias[4];
#pragma unroll
  for (int g = 0; g < 4; ++g)
    bias[g] = bsum[dir * 1024 + g * 256 + slice * 64 + wv * 16 + c];
  half8 breg[4][12];
#pragma unroll
  for (int g = 0; g < 4; ++g) {
    int nt = wv + 4 * g;
#pragma unroll
    for (int kt = 0; kt < 12; ++kt)
      breg[g][kt] = *(const half8*)(Wall + (((size_t)(ds * 16 + nt) * 12 + kt) * 64 + lane) * 8);
  }
  float creg[4];
#pragma unroll
  for (int i = 0; i < 4; ++i) creg[i] = 0.f;
  __syncthreads();
  {  // x_0 for this batch-quarter (16 batches x 16 ch = 256 loads)
    int l0 = dir ? (L - 1) : 0;
    int bl = tid >> 4, ch = tid & 15;
    *(half8*)&Ash[bl][ch * 8] =
        *(const half8*)(expb + ((size_t)(bq * 16 + bl) * L + l0) * EMB_ + ch * 8);
  }
  __syncthreads();

  for (int s = 0; s < L; ++s) {
    int l_io = dir ? (L - 1 - s) : s;
    // --- p0: issue poll set-1 for remote h_{s-1} + x(s+1) prefetch ---
    unsigned int v[6];
    const unsigned int* rp = nullptr;
    if (s > 0) {
      int l_prev = dir ? (L - s) : (s - 1);
      rp = mail32 + ((size_t)(l_prev * 2 + dir) * 64 + cb) * 128;
#pragma unroll
      for (int wd = 0; wd < 6; ++wd)
        v[wd] = __hip_atomic_load(rp + jm_[wd], __ATOMIC_RELAXED, __HIP_MEMORY_SCOPE_AGENT);
    }
    half8 xr;
    if (s + 1 < L) {
      int l1 = dir ? (L - 2 - s) : (s + 1);
      int bl = tid >> 4, ch = tid & 15;
      xr = *(const half8*)(expb + ((size_t)(bq * 16 + bl) * L + l1) * EMB_ + ch * 8);
    }
    // --- p1: GEMM-A (x_s + own h_{s-1}), overlaps set-1 flight ---
    f32x4 acc[4];
#pragma unroll
    for (int g = 0; g < 4; ++g) acc[g] = f32x4{0.f, 0.f, 0.f, 0.f};
#pragma unroll
    for (int kt = 0; kt < 6; ++kt) {
      half8 a = *(const half8*)&Ash[c][kt * 32 + kg * 8];
#pragma unroll
      for (int g = 0; g < 4; ++g)
        acc[g] = __builtin_amdgcn_mfma_f32_16x16x32_f16(a, breg[g][kt], acc[g], 0, 0, 0);
    }
    // --- p2: pipelined validate: issue set-2, check set-1, merge, then loop ---
    if (s > 0) {
      unsigned int w2[6];
#pragma unroll
      for (int wd = 0; wd < 6; ++wd)
        w2[wd] = __hip_atomic_load(rp + jm_[wd], __ATOMIC_RELAXED, __HIP_MEMORY_SCOPE_AGENT);
      int miss = 0;
#pragma unroll
      for (int wd = 0; wd < 6; ++wd) miss |= (v[wd] == 0xFFFFFFFFu) ? 1 : 0;
      if (__any(miss)) {
        // merge set-2 (already in flight ~ GEMM-A duration)
#pragma unroll
        for (int wd = 0; wd < 6; ++wd)
          if (v[wd] == 0xFFFFFFFFu) v[wd] = w2[wd];
        while (true) {
          miss = 0;
#pragma unroll
          for (int wd = 0; wd < 6; ++wd) miss |= (v[wd] == 0xFFFFFFFFu) ? 1 : 0;
          if (!__any(miss)) break;
          __builtin_amdgcn_s_sleep(1);
          unsigned int w3[6];
#pragma unroll
          for (int wd = 0; wd < 6; ++wd)
            w3[wd] = __hip_atomic_load(rp + jm_[wd], __ATOMIC_RELAXED, __HIP_MEMORY_SCOPE_AGENT);
#pragma unroll
          for (int wd = 0; wd < 6; ++wd)
            if (v[wd] == 0xFFFFFFFFu) v[wd] = w3[wd];
        }
      }
      unsigned int* ar = (unsigned int*)&Ash[rbl][0];
#pragma unroll
      for (int wd = 0; wd < 6; ++wd) {
        int jm = jm_[wd];
        int ps = jm >> 5;
        int rr = ps - (ps > slice ? 1 : 0);
        ar[96 + rr * 32 + (jm & 31)] = v[wd];
      }
    }
    barrier_lds();  // B1
    // --- p3: x(s+1) -> Ash (region free after GEMM-A) ---
    if (s + 1 < L) {
      int bl = tid >> 4, ch = tid & 15;
      *(half8*)&Ash[bl][ch * 8] = xr;
    }
    // --- p4: GEMM-B (remote h) ---
#pragma unroll
    for (int kt = 6; kt < 12; ++kt) {
      half8 a = *(const half8*)&Ash[c][kt * 32 + kg * 8];
#pragma unroll
      for (int g = 0; g < 4; ++g)
        acc[g] = __builtin_amdgcn_mfma_f32_16x16x32_f16(a, breg[g][kt], acc[g], 0, 0, 0);
    }
    // --- p5: cell update (exp2/rcp raw-HW nonlins; pre-acts log2e-scaled) ---
    _Float16 hv[4];
#pragma unroll
    for (int i = 0; i < 4; ++i) {
      float iv = acc[0][i] + bias[0];
      float fv = acc[1][i] + bias[1];
      float gv = acc[2][i] + bias[2];
      float ov = acc[3][i] + bias[3];
      float cc = sig2(fv) * creg[i] + sig2(iv) * tanh2(2.f * gv);
      float hh = sig2(ov) * tanh2(2.f * LOG2E * cc);
      creg[i] = cc;
      hv[i] = (_Float16)hh;
    }
    // --- p6: publish h_s (pair-packed u32, relaxed agent, never drained) ---
#pragma unroll
    for (int i = 0; i < 4; ++i) {
      unsigned int mine = (unsigned int)__builtin_bit_cast(unsigned short, hv[i]);
      unsigned int part = (unsigned int)(unsigned)__shfl_xor((int)mine, 1, 64);
      unsigned int word = mine | (part << 16);
      if ((c & 1) == 0) {
        int b = bq * 16 + kg * 4 + i;
        __hip_atomic_store(
            mail32 + ((size_t)(l_io * 2 + dir) * 64 + b) * 128 + slice * 32 + wv * 8 + (c >> 1),
            word, __ATOMIC_RELAXED, __HIP_MEMORY_SCOPE_AGENT);
      }
    }
    // --- p7: own h -> Ash ---
#pragma unroll
    for (int i = 0; i < 4; ++i)
      Ash[kg * 4 + i][EMB_ + wv * 16 + c] = hv[i];
    barrier_lds();  // B2
  }
}

// out[r,:80] = h(b,l) @ lin_w.T + lin_b, reading from mailbox [l][dir][b][u]
__global__ __launch_bounds__(256) void k_linear(
    const _Float16* __restrict__ mail, const _Float16* __restrict__ linWp,
    const float* __restrict__ lin_b, float* __restrict__ out, int L) {
  int tid = threadIdx.x;
  int wv = tid >> 6, lane = tid & 63;
  int arow = lane & 15, kgrp = lane >> 4;
  int mt = blockIdx.x * 4 + wv;  // < 4L
  int r0 = mt * 16 + arow;       // A-row = b*L + l
  int b = r0 / L, l = r0 - b * L;
  const _Float16* base0 = mail + ((size_t)(l * 2 + 0) * 64 + b) * 256 + kgrp * 8;
  const _Float16* base1 = mail + ((size_t)(l * 2 + 1) * 64 + b) * 256 + kgrp * 8;
  half8 a[16];
#pragma unroll
  for (int kt = 0; kt < 8; ++kt) a[kt] = *(const half8*)(base0 + kt * 32);
#pragma unroll
  for (int kt = 8; kt < 16; ++kt) a[kt] = *(const half8*)(base1 + (kt - 8) * 32);
#pragma unroll
  for (int nt = 0; nt < 5; ++nt) {
    f32x4 acc = {0.f, 0.f, 0.f, 0.f};
    const half8* Bp = (const half8*)(linWp + (size_t)nt * 16 * 512) + lane;
#pragma unroll
    for (int kt = 0; kt < 16; ++kt)
      acc = __builtin_amdgcn_mfma_f32_16x16x32_f16(a[kt], Bp[kt * 64], acc, 0, 0, 0);
    int col = nt * 16 + arow;
    float bb = lin_b[col];
#pragma unroll
    for (int i = 0; i < 4; ++i)
      out[(size_t)(mt * 16 + kgrp * 4 + i) * MEL_ + col] = acc[i] + bb;
  }
}

extern "C" void kernel_launch(void* const* d_in, const int* in_sizes, int n_in,
                              void* d_out, int out_size, void* d_ws, size_t ws_size,
                              hipStream_t stream) {
  const int* x = (const int*)d_in[0];
  const float* embed = (const float*)d_in[1];
  const float* dp_w = (const float*)d_in[2];
  const float* dp_b = (const float*)d_in[3];
  const float* wih_f = (const float*)d_in[4];
  const float* whh_f = (const float*)d_in[5];
  const float* bih_f = (const float*)d_in[6];
  const float* bhh_f = (const float*)d_in[7];
  const float* wih_b = (const float*)d_in[8];
  const float* whh_b = (const float*)d_in[9];
  const float* bih_b = (const float*)d_in[10];
  const float* bhh_b = (const float*)d_in[11];
  const float* lin_w = (const float*)d_in[12];
  const float* lin_b = (const float*)d_in[13];
  float* out = (float*)d_out;
  (void)in_sizes; (void)n_in; (void)ws_size;

  int L = out_size / (B_ * MEL_);
  char* base = (char*)d_ws;
  size_t o = 0;
  auto take = [&](size_t bytes) {
    void* p = base + o;
    o = (o + bytes + 255) & ~(size_t)255;
    return p;
  };
  int* dur = (int*)take((size_t)B_ * T_ * 4);
  int* cum = (int*)take((size_t)B_ * T_ * 4);
  int* idx = (int*)take((size_t)B_ * L * 4);
  _Float16* Wall = (_Float16*)take((size_t)8 * 16 * 12 * 512 * 2);
  float* bsum = (float*)take(2048 * 4);
  _Float16* linWp = (_Float16*)take((size_t)5 * 16 * 512 * 2);
  _Float16* expb = (_Float16*)take((size_t)B_ * L * EMB_ * 2);
  _Float16* mail = (_Float16*)take((size_t)L * 2 * 64 * 256 * 2);

  hipLaunchKernelGGL(k_pack_wall, dim3(384), dim3(256), 0, stream, wih_f, whh_f, wih_b, whh_b, Wall);
  hipLaunchKernelGGL(k_pack_misc, dim3(28), dim3(256), 0, stream, bih_f, bhh_f, bih_b, bhh_b,
                     lin_w, bsum, linWp);
  hipLaunchKernelGGL(k_dur, dim3(128), dim3(256), 0, stream, x, embed, dp_w, dp_b, dur);
  hipLaunchKernelGGL(k_scan, dim3(64), dim3(512), 0, stream, dur, cum);
  hipLaunchKernelGGL(k_fill, dim3((B_ * L + 255) / 256), dim3(256), 0, stream, idx, B_ * L, -1);
  {
    int n4 = L * 4096;  // mailbox u32 count / 4
    hipLaunchKernelGGL(k_fill_sent, dim3((n4 + 255) / 256), dim3(256), 0, stream,
                       (unsigned int*)mail, n4);
  }
  hipLaunchKernelGGL(k_scatter, dim3(64), dim3(512), 0, stream, cum, idx, L);
  hipLaunchKernelGGL(k_expand, dim3((B_ * L * 16 + 255) / 256), dim3(256), 0, stream,
                     x, embed, idx, expb, L);
  hipLaunchKernelGGL(k_rec, dim3(32), dim3(256), 0, stream, expb, Wall, bsum, mail, L);
  hipLaunchKernelGGL(k_linear, dim3(L), dim3(256), 0, stream, mail, linWp, lin_b, out, L);
}